// Round 10
// baseline (284.798 us; speedup 1.0000x reference)
//
#include <hip/hip_runtime.h>

// DEChannelPool: 6 soft-morphology branches + per-channel BN + 1x1 conv + BN + ReLU.
// Trick 1: exp(beta*(w±x)) = exp(beta*w)*exp(±beta*x): 2 exps per input pixel.
// Trick 2: BN+conv fold to alpha*log2(S) + const; const cancels in final scalar BN.
// R8: 2-col/thread b64 stats; pipeline gap-dominated at 6 stream ops (282 us).
// R9: 3-op version FAILED: last-block finisher read other blocks' slab stores with
//     plain loads -> cross-XCD L2 non-coherence -> stale data (absmax 0.31).
// R10: rollback to the coherent design: kernel boundary IS the fence. 4 stream ops:
//     k_stats (inline wexp + partial plain-stores + scal zero) -> k_reduce (alpha
//     in-block, slab stores only) -> k_fsum (slab sum + scalar moments, coherent
//     because post-boundary) -> k_final (slab re-sum + scalar BN + ReLU).

#define BETA 15.0f
#define MSHIFT 25.0f
#define INV_BETA (1.0f/15.0f)
#define LN2 0.6931471805599453f
#define EPSB 1e-5f
#define Hn 192
#define Wn 192
#define HWn (192*192)
#define N1 (8*192*192)
#define SFLOOR 1e-37f

// ---- stats geometry: 64r x 64c tile, 8-row strips x 2-col threads, 256 thr ----
#define STDH 70
#define STSTR 72            // even stride: b64-aligned pairs
#define SNPAIR (STDH*35)    // 2450 col-pairs

// ---- reduce geometry: 32r x 32c tile, 4-row strips, 256 thr, BOTH sides ----
#define RDH 38
#define RSTR 40
#define RNPAIR (RDH*19)     // 722 col-pairs
#define RPITER 3

// workspace layout (float offsets)
#define WS_PART_S 0                    // [6 slots][64 c][72 = t*8+b]
#define WS_PART_Q 27648
#define WS_SCAL   55296                // 4 floats
#define WS_WG     55300                // 3456
#define WS_SLAB   58756                // [2 sides * NS][8 b][HWn]

// ---- single-column register-rotating stencil (reduce kernel) ----
template<int D, int H, int STR>
__device__ __forceinline__ void sweepT(const float* __restrict__ P,
                                       int py0, int px,
                                       const float* __restrict__ wgp,
                                       float* __restrict__ S) {
    float W[9];
#pragma unroll
    for (int k2 = 0; k2 < 9; ++k2) W[k2] = wgp[k2];
#pragma unroll
    for (int k = 0; k < H; ++k) S[k] = 0.f;
    const float* base = P + (py0 - D + 3) * STR + (px - D);
#pragma unroll
    for (int r = 0; r < H + 2 * D; ++r) {
        float va = base[r * STR];
        float vb = base[r * STR + D];
        float vc = base[r * STR + 2 * D];
#pragma unroll
        for (int i = 0; i < 3; ++i) {
            int k = r - i * D;
            if (k >= 0 && k < H) {
                S[k] = fmaf(W[i*3+0], va, S[k]);
                S[k] = fmaf(W[i*3+1], vb, S[k]);
                S[k] = fmaf(W[i*3+2], vc, S[k]);
            }
        }
    }
}

// ---- 2-column register-rotating stencil (stats kernel), b64 plane reads ----
template<int D>
__device__ __forceinline__ void sweep2(const float* __restrict__ P,
                                       int py0, int tcol,
                                       const float* __restrict__ wgp,
                                       float* __restrict__ SA,
                                       float* __restrict__ SB) {
    float W[9];
#pragma unroll
    for (int k2 = 0; k2 < 9; ++k2) W[k2] = wgp[k2];
#pragma unroll
    for (int k = 0; k < 8; ++k) { SA[k] = 0.f; SB[k] = 0.f; }
    const int colbase = (D == 1) ? (2 * tcol + 2) : (2 * tcol);
#pragma unroll
    for (int r = 0; r < 8 + 2 * D; ++r) {
        const float2* row =
            (const float2*)(P + (py0 - D + 3 + r) * STSTR + colbase);
        float2 v0 = row[0], v1 = row[1];
        float ta0, ta1, ta2, tb0, tb1, tb2;
        if (D == 1) {
            ta0 = v0.x; ta1 = v0.y; ta2 = v1.x;
            tb0 = v0.y; tb1 = v1.x; tb2 = v1.y;
        } else {
            float2 v2 = row[2], v3 = row[3];
            if (D == 2) {
                ta0 = v0.y; ta1 = v1.y; ta2 = v2.y;
                tb0 = v1.x; tb1 = v2.x; tb2 = v3.x;
            } else {
                ta0 = v0.x; ta1 = v1.y; ta2 = v3.x;
                tb0 = v0.y; tb1 = v2.x; tb2 = v3.y;
            }
        }
#pragma unroll
        for (int i = 0; i < 3; ++i) {
            int k = r - i * D;
            if (k >= 0 && k < 8) {
                SA[k] = fmaf(W[i*3+0], ta0, SA[k]);
                SA[k] = fmaf(W[i*3+1], ta1, SA[k]);
                SA[k] = fmaf(W[i*3+2], ta2, SA[k]);
                SB[k] = fmaf(W[i*3+0], tb0, SB[k]);
                SB[k] = fmaf(W[i*3+1], tb1, SB[k]);
                SB[k] = fmaf(W[i*3+2], tb2, SB[k]);
            }
        }
    }
}

__device__ __forceinline__ void red2(float a, float b2, int lane, float* rs, float* rq) {
#pragma unroll
    for (int off = 32; off; off >>= 1) {
        a  += __shfl_down(a, off, 64);
        b2 += __shfl_down(b2, off, 64);
    }
    if (lane == 0) { *rs = a; *rq = b2; }
}

// grid (9 tiles, 512 b*c), 256 threads. 64x64 tile, both sides, 16 px/thread.
// Plain-store partials; inline wexp (publishes wg); block (0,0) zeroes scal.
__global__ __launch_bounds__(256, 3) void k_stats(
    const float* __restrict__ x,
    const float* __restrict__ we, const float* __restrict__ wd,
    float* __restrict__ part_s, float* __restrict__ part_q,
    float* __restrict__ wg, float* __restrict__ scal) {
    __shared__ float EX[STDH * STSTR], EY[STDH * STSTR];
    __shared__ float wgl[54];
    __shared__ float redS[4][6], redQ[4][6];
    const int tid = threadIdx.x;
    const int p = blockIdx.y;            // b*64 + c
    const int c = p & 63;
    const int b = p >> 6;
    const int t = blockIdx.x;
    const int h0 = (t / 3) * 64, w0 = (t % 3) * 64;

    if (t == 0 && p == 0 && tid < 4) scal[tid] = 0.f;   // for k_fsum (post-boundary)
    if (tid < 54) {                       // this channel's 54 exp'd weights
        int slot = tid / 9, k = tid - slot * 9;
        const float* wsrc = (slot < 3) ? we : wd;
        int br = (slot < 3) ? slot : slot - 3;
        float v = __expf(BETA * wsrc[br * 576 + c * 9 + k]);
        wgl[tid] = v;
        if (t == 0) wg[slot * 576 + c * 9 + k] = v;   // publish for k_reduce (dup-safe)
    }

    const float* xp = x + (size_t)p * HWn;
    {   // pair loader: float2 writes to both planes
        int r = tid / 35, pp = tid - r * 35;
        for (int l = tid; l < SNPAIR; l += 256) {
            int gh = h0 - 3 + r;
            int gw0 = w0 - 3 + 2 * pp;
            float va = 0.f, vb = 0.f;
            if ((unsigned)gh < (unsigned)Hn) {
                if ((unsigned)gw0 < (unsigned)Wn)       va = xp[gh * Wn + gw0];
                if ((unsigned)(gw0+1) < (unsigned)Wn)   vb = xp[gh * Wn + gw0 + 1];
            }
            float ba = BETA * va, bb = BETA * vb;   // OOB -> 0 -> exp(-M), correct
            *(float2*)&EX[r * STSTR + 2 * pp] =
                make_float2(__expf(-ba - MSHIFT), __expf(-bb - MSHIFT));
            *(float2*)&EY[r * STSTR + 2 * pp] =
                make_float2(__expf( ba - MSHIFT), __expf( bb - MSHIFT));
            r += 7; pp += 11;            // 256 = 7*35 + 11
            if (pp >= 35) { pp -= 35; ++r; }
        }
    }
    __syncthreads();

    const int tcol = tid & 31;
    const int py0 = (tid >> 5) * 8;
    const int lane = tid & 63, wv = tid >> 6;
    const float LI = LN2 * INV_BETA, MI = MSHIFT * INV_BETA;

#define DO_BR_STATS(D, SLOT, PL, AL, AM) { \
    float SA[8], SB[8]; \
    sweep2<D>(PL, py0, tcol, &wgl[(SLOT) * 9], SA, SB); \
    float sv = 0.f, qv = 0.f; \
    _Pragma("unroll") \
    for (int k = 0; k < 8; ++k) { \
        float ma = fmaf(__log2f(fmaxf(SA[k], SFLOOR)), AL, AM); \
        float mb = fmaf(__log2f(fmaxf(SB[k], SFLOOR)), AL, AM); \
        sv += ma + mb; qv = fmaf(ma, ma, fmaf(mb, mb, qv)); \
    } \
    red2(sv, qv, lane, &redS[wv][SLOT], &redQ[wv][SLOT]); }

    DO_BR_STATS(1, 0, EX, -LI, -MI)
    DO_BR_STATS(2, 1, EX, -LI, -MI)
    DO_BR_STATS(3, 2, EX, -LI, -MI)
    DO_BR_STATS(1, 3, EY,  LI,  MI)
    DO_BR_STATS(2, 4, EY,  LI,  MI)
    DO_BR_STATS(3, 5, EY,  LI,  MI)
#undef DO_BR_STATS

    __syncthreads();
    if (tid < 6)
        part_s[(tid * 64 + c) * 72 + t * 8 + b] =
            redS[0][tid] + redS[1][tid] + redS[2][tid] + redS[3][tid];
    else if (tid < 12) {
        int v = tid - 6;
        part_q[(v * 64 + c) * 72 + t * 8 + b] =
            redQ[0][v] + redQ[1][v] + redQ[2][v] + redQ[3][v];
    }
}

// grid (36 tiles, 8 b, NS grps), 256 threads. 32x32 tile, NC channels, both sides.
// alpha from partials in-block; slab plain stores ONLY (coherence via kernel bound).
template<int NS>
__global__ __launch_bounds__(256, 4) void k_reduce(
    const float* __restrict__ x, const float* __restrict__ wg,
    const float* __restrict__ part_s, const float* __restrict__ part_q,
    const float* __restrict__ bn_ge, const float* __restrict__ bn_gd,
    const float* __restrict__ conve, const float* __restrict__ convd,
    float* __restrict__ slab) {
    constexpr int NC = 64 / NS;
    __shared__ float EX[RDH * RSTR], EY[RDH * RSTR];
    __shared__ float al[384];
    const int tid = threadIdx.x;
    const int t = blockIdx.x;
    const int b = blockIdx.y;
    const int grp = blockIdx.z;
    const int c0 = grp * NC;
    const int tr = t / 6, tc = t - tr * 6;
    const int h0 = tr * 32, w0 = tc * 32;
    const int px = (tid & 31) + 3;
    const int py0 = (tid >> 5) * 4;
    const float* xb = x + (size_t)b * 64 * HWn;

    // alpha for this block's channels only: 6 slots x NC channels
    for (int l = tid; l < 6 * NC; l += 256) {
        int slot = l / NC, cl = l - slot * NC;
        int ai = slot * 64 + c0 + cl;    // al index = side*192 + br*64 + c
        const float* ps = part_s + (size_t)ai * 72;
        const float* pq = part_q + (size_t)ai * 72;
        float s = 0.f, q = 0.f;
#pragma unroll
        for (int j = 0; j < 72; ++j) { s += ps[j]; q += pq[j]; }
        float mean = s * (1.0f / N1);
        float var  = q * (1.0f / N1) - mean * mean;
        float inv  = rsqrtf(fmaxf(var, 0.f) + EPSB);
        int side_ = slot / 3, ch = ai - side_ * 192;
        float g  = side_ ? bn_gd[ch] : bn_ge[ch];
        float cw = side_ ? convd[ch] : conve[ch];
        float sgn = side_ ? 1.f : -1.f;
        al[ai] = sgn * cw * g * inv * INV_BETA * LN2;
    }

    float accE[4] = {0.f, 0.f, 0.f, 0.f}, accD[4] = {0.f, 0.f, 0.f, 0.f};
    float2 L[RPITER];

    {   // prologue: prefetch channel c0 (raw x pairs)
        const float* xp = xb + (size_t)c0 * HWn;
        int r = tid / 19, pp = tid - r * 19;
#pragma unroll
        for (int i = 0; i < RPITER; ++i) {
            int l = tid + i * 256;
            float va = 0.f, vb = 0.f;
            if (l < RNPAIR) {
                int gh = h0 - 3 + r, gw0 = w0 - 3 + 2 * pp;
                if ((unsigned)gh < (unsigned)Hn) {
                    if ((unsigned)gw0 < (unsigned)Wn)     va = xp[gh * Wn + gw0];
                    if ((unsigned)(gw0+1) < (unsigned)Wn) vb = xp[gh * Wn + gw0 + 1];
                }
            }
            L[i] = make_float2(va, vb);
            r += 13; pp += 9;            // 256 = 13*19 + 9
            if (pp >= 19) { pp -= 19; ++r; }
        }
    }

    for (int ci = 0; ci < NC; ++ci) {
        __syncthreads();                  // planes free (iter 0: al visible)
        {
            int r = tid / 19, pp = tid - r * 19;
#pragma unroll
            for (int i = 0; i < RPITER; ++i) {
                int l = tid + i * 256;
                if (l < RNPAIR) {
                    float ba = BETA * L[i].x, bb = BETA * L[i].y;
                    *(float2*)&EX[r * RSTR + 2 * pp] =
                        make_float2(__expf(-ba - MSHIFT), __expf(-bb - MSHIFT));
                    *(float2*)&EY[r * RSTR + 2 * pp] =
                        make_float2(__expf( ba - MSHIFT), __expf( bb - MSHIFT));
                }
                r += 13; pp += 9;
                if (pp >= 19) { pp -= 19; ++r; }
            }
        }
        __syncthreads();
        if (ci < NC - 1) {                // prefetch next channel
            const float* xp = xb + (size_t)(c0 + ci + 1) * HWn;
            int r = tid / 19, pp = tid - r * 19;
#pragma unroll
            for (int i = 0; i < RPITER; ++i) {
                int l = tid + i * 256;
                float va = 0.f, vb = 0.f;
                if (l < RNPAIR) {
                    int gh = h0 - 3 + r, gw0 = w0 - 3 + 2 * pp;
                    if ((unsigned)gh < (unsigned)Hn) {
                        if ((unsigned)gw0 < (unsigned)Wn)     va = xp[gh * Wn + gw0];
                        if ((unsigned)(gw0+1) < (unsigned)Wn) vb = xp[gh * Wn + gw0 + 1];
                    }
                }
                L[i] = make_float2(va, vb);
                r += 13; pp += 9;
                if (pp >= 19) { pp -= 19; ++r; }
            }
        }
        const int c = c0 + ci;
#define DO_BR_ACC(D, SIDE, BR, PL, ACC) { \
        float S[4]; \
        sweepT<D, 4, RSTR>(PL, py0, px, wg + ((SIDE) * 3 + (BR)) * 576 + c * 9, S); \
        const float a_ = al[(SIDE) * 192 + (BR) * 64 + c]; \
        _Pragma("unroll") \
        for (int k = 0; k < 4; ++k) \
            ACC[k] = fmaf(a_, __log2f(fmaxf(S[k], SFLOOR)), ACC[k]); }

        DO_BR_ACC(1, 0, 0, EX, accE)
        DO_BR_ACC(2, 0, 1, EX, accE)
        DO_BR_ACC(3, 0, 2, EX, accE)
        DO_BR_ACC(1, 1, 0, EY, accD)
        DO_BR_ACC(2, 1, 1, EY, accD)
        DO_BR_ACC(3, 1, 2, EY, accD)
#undef DO_BR_ACC
    }

    // slab stores (plain, chunk-private; made visible by the kernel boundary)
    float* pe = slab + ((size_t)(grp * 8 + b)) * HWn;
    float* pd = slab + ((size_t)((NS + grp) * 8 + b)) * HWn;
    const int oidx = (h0 + py0) * Wn + (w0 + px - 3);
#pragma unroll
    for (int k = 0; k < 4; ++k) {
        pe[oidx + k * Wn] = accE[k];
        pd[oidx + k * Wn] = accD[k];
    }
}

// sums NS slab groups per pixel -> scalar-BN moments (coherent: post-boundary reads).
template<int NS>
__global__ __launch_bounds__(256) void k_fsum(
    const float* __restrict__ slab, float* __restrict__ scal) {
    int i = blockIdx.x * 256 + threadIdx.x;   // < 294912
    int b = i / HWn, rem = i - b * HWn;
    float e = 0.f, d = 0.f;
#pragma unroll
    for (int g = 0; g < NS; ++g) {
        e += slab[((size_t)(g * 8 + b)) * HWn + rem];
        d += slab[((size_t)((NS + g) * 8 + b)) * HWn + rem];
    }
    float v[4] = {e, e * e, d, d * d};
    __shared__ float red[4][4];
    int lane = threadIdx.x & 63, wv = threadIdx.x >> 6;
#pragma unroll
    for (int k = 0; k < 4; ++k) {
        float tv = v[k];
#pragma unroll
        for (int off = 32; off; off >>= 1) tv += __shfl_down(tv, off, 64);
        if (lane == 0) red[wv][k] = tv;
    }
    __syncthreads();
    if (threadIdx.x < 4)
        atomicAdd(&scal[threadIdx.x],
                  red[0][threadIdx.x] + red[1][threadIdx.x] + red[2][threadIdx.x] + red[3][threadIdx.x]);
}

// re-sums slabs per pixel, applies the scalar BN + ReLU, writes out.
template<int NS>
__global__ __launch_bounds__(256) void k_final(
    const float* __restrict__ slab, const float* __restrict__ scal,
    const float* __restrict__ g_e, const float* __restrict__ b_e,
    const float* __restrict__ g_d, const float* __restrict__ b_d,
    float* __restrict__ out) {
    int i = blockIdx.x * 256 + threadIdx.x;  // < 294912
    int b = i / HWn, rem = i - b * HWn;
    float e = 0.f, d = 0.f;
#pragma unroll
    for (int g = 0; g < NS; ++g) {
        e += slab[((size_t)(g * 8 + b)) * HWn + rem];
        d += slab[((size_t)((NS + g) * 8 + b)) * HWn + rem];
    }
    float me_ = scal[0] * (1.0f / N1);
    float ve  = scal[1] * (1.0f / N1) - me_ * me_;
    float ie  = rsqrtf(fmaxf(ve, 0.f) + EPSB);
    float md_ = scal[2] * (1.0f / N1);
    float vd  = scal[3] * (1.0f / N1) - md_ * md_;
    float idv = rsqrtf(fmaxf(vd, 0.f) + EPSB);
    float oe = fmaxf(g_e[0] * (e - me_) * ie + b_e[0], 0.f);
    float od = fmaxf(g_d[0] * (d - md_) * idv + b_d[0], 0.f);
    out[(size_t)(b * 2) * HWn + rem]     = oe;
    out[(size_t)(b * 2 + 1) * HWn + rem] = od;
}

extern "C" void kernel_launch(void* const* d_in, const int* in_sizes, int n_in,
                              void* d_out, int out_size, void* d_ws, size_t ws_size,
                              hipStream_t stream) {
    const float* x     = (const float*)d_in[0];
    const float* we    = (const float*)d_in[1];
    const float* wd    = (const float*)d_in[2];
    const float* bn_ge = (const float*)d_in[3];
    const float* bn_gd = (const float*)d_in[5];
    const float* conve = (const float*)d_in[7];
    const float* convd = (const float*)d_in[8];
    const float* g_e   = (const float*)d_in[9];
    const float* b_e   = (const float*)d_in[10];
    const float* g_d   = (const float*)d_in[11];
    const float* b_d   = (const float*)d_in[12];
    float* ws = (float*)d_ws;

    float* part_s = ws + WS_PART_S;
    float* part_q = ws + WS_PART_Q;
    float* scal   = ws + WS_SCAL;
    float* wg     = ws + WS_WG;
    float* slab   = ws + WS_SLAB;

    const size_t need4 = (size_t)(WS_SLAB + 8 * 294912) * sizeof(float); // 9.7 MB
    const size_t need2 = (size_t)(WS_SLAB + 4 * 294912) * sizeof(float); // 5.0 MB
    const int ns = (ws_size >= need4) ? 4 : (ws_size >= need2) ? 2 : 1;

    hipLaunchKernelGGL(k_stats, dim3(9, 512), dim3(256), 0, stream,
                       x, we, wd, part_s, part_q, wg, scal);
    if (ns == 4) {
        hipLaunchKernelGGL((k_reduce<4>), dim3(36, 8, 4), dim3(256), 0, stream,
                           x, wg, part_s, part_q, bn_ge, bn_gd, conve, convd, slab);
        hipLaunchKernelGGL((k_fsum<4>), dim3(1152), dim3(256), 0, stream, slab, scal);
        hipLaunchKernelGGL((k_final<4>), dim3(1152), dim3(256), 0, stream,
                           slab, scal, g_e, b_e, g_d, b_d, (float*)d_out);
    } else if (ns == 2) {
        hipLaunchKernelGGL((k_reduce<2>), dim3(36, 8, 2), dim3(256), 0, stream,
                           x, wg, part_s, part_q, bn_ge, bn_gd, conve, convd, slab);
        hipLaunchKernelGGL((k_fsum<2>), dim3(1152), dim3(256), 0, stream, slab, scal);
        hipLaunchKernelGGL((k_final<2>), dim3(1152), dim3(256), 0, stream,
                           slab, scal, g_e, b_e, g_d, b_d, (float*)d_out);
    } else {
        hipLaunchKernelGGL((k_reduce<1>), dim3(36, 8, 1), dim3(256), 0, stream,
                           x, wg, part_s, part_q, bn_ge, bn_gd, conve, convd, slab);
        hipLaunchKernelGGL((k_fsum<1>), dim3(1152), dim3(256), 0, stream, slab, scal);
        hipLaunchKernelGGL((k_final<1>), dim3(1152), dim3(256), 0, stream,
                           slab, scal, g_e, b_e, g_d, b_d, (float*)d_out);
    }
}

// Round 11
// 283.981 us; speedup vs baseline: 1.0029x; 1.0029x over previous
//
#include <hip/hip_runtime.h>

// DEChannelPool: 6 soft-morphology branches + per-channel BN + 1x1 conv + BN + ReLU.
// Trick 1: exp(beta*(w±x)) = exp(beta*w)*exp(±beta*x): 2 exps per input pixel.
// Trick 2: BN+conv fold to alpha*log2(S) + const; const cancels in final scalar BN.
// R10: coherent 4-op pipeline (stats -> reduce -> fsum -> final), 284.8 us.
//      Learning: wall = kernel-sum + ~85 us invariant (ops count doesn't matter).
// R11: k_reduce balance fix. 1152 blocks = 4.5/CU meant half the CUs ran a 5th
//      block while half idled (Occupancy 28%, VALUBusy 51%). Now 24x32 tiles ->
//      48x8x4 = 1536 blocks = EXACTLY 6 blocks/CU, launch_bounds(256,6) for
//      24 resident waves/CU. Everything else byte-identical to R10.

#define BETA 15.0f
#define MSHIFT 25.0f
#define INV_BETA (1.0f/15.0f)
#define LN2 0.6931471805599453f
#define EPSB 1e-5f
#define Hn 192
#define Wn 192
#define HWn (192*192)
#define N1 (8*192*192)
#define SFLOOR 1e-37f

// ---- stats geometry: 64r x 64c tile, 8-row strips x 2-col threads, 256 thr ----
#define STDH 70
#define STSTR 72            // even stride: b64-aligned pairs
#define SNPAIR (STDH*35)    // 2450 col-pairs

// ---- reduce geometry: 24r x 32c tile, 3-row strips, 256 thr, BOTH sides ----
#define RDH 30              // 24 + 2*3
#define RSTR 40
#define RNPAIR (RDH*19)     // 570 col-pairs
#define RPITER 3

// workspace layout (float offsets)
#define WS_PART_S 0                    // [6 slots][64 c][72 = t*8+b]
#define WS_PART_Q 27648
#define WS_SCAL   55296                // 4 floats
#define WS_WG     55300                // 3456
#define WS_SLAB   58756                // [2 sides * NS][8 b][HWn]

// ---- single-column register-rotating stencil (reduce kernel) ----
template<int D, int H, int STR>
__device__ __forceinline__ void sweepT(const float* __restrict__ P,
                                       int py0, int px,
                                       const float* __restrict__ wgp,
                                       float* __restrict__ S) {
    float W[9];
#pragma unroll
    for (int k2 = 0; k2 < 9; ++k2) W[k2] = wgp[k2];
#pragma unroll
    for (int k = 0; k < H; ++k) S[k] = 0.f;
    const float* base = P + (py0 - D + 3) * STR + (px - D);
#pragma unroll
    for (int r = 0; r < H + 2 * D; ++r) {
        float va = base[r * STR];
        float vb = base[r * STR + D];
        float vc = base[r * STR + 2 * D];
#pragma unroll
        for (int i = 0; i < 3; ++i) {
            int k = r - i * D;
            if (k >= 0 && k < H) {
                S[k] = fmaf(W[i*3+0], va, S[k]);
                S[k] = fmaf(W[i*3+1], vb, S[k]);
                S[k] = fmaf(W[i*3+2], vc, S[k]);
            }
        }
    }
}

// ---- 2-column register-rotating stencil (stats kernel), b64 plane reads ----
template<int D>
__device__ __forceinline__ void sweep2(const float* __restrict__ P,
                                       int py0, int tcol,
                                       const float* __restrict__ wgp,
                                       float* __restrict__ SA,
                                       float* __restrict__ SB) {
    float W[9];
#pragma unroll
    for (int k2 = 0; k2 < 9; ++k2) W[k2] = wgp[k2];
#pragma unroll
    for (int k = 0; k < 8; ++k) { SA[k] = 0.f; SB[k] = 0.f; }
    const int colbase = (D == 1) ? (2 * tcol + 2) : (2 * tcol);
#pragma unroll
    for (int r = 0; r < 8 + 2 * D; ++r) {
        const float2* row =
            (const float2*)(P + (py0 - D + 3 + r) * STSTR + colbase);
        float2 v0 = row[0], v1 = row[1];
        float ta0, ta1, ta2, tb0, tb1, tb2;
        if (D == 1) {
            ta0 = v0.x; ta1 = v0.y; ta2 = v1.x;
            tb0 = v0.y; tb1 = v1.x; tb2 = v1.y;
        } else {
            float2 v2 = row[2], v3 = row[3];
            if (D == 2) {
                ta0 = v0.y; ta1 = v1.y; ta2 = v2.y;
                tb0 = v1.x; tb1 = v2.x; tb2 = v3.x;
            } else {
                ta0 = v0.x; ta1 = v1.y; ta2 = v3.x;
                tb0 = v0.y; tb1 = v2.x; tb2 = v3.y;
            }
        }
#pragma unroll
        for (int i = 0; i < 3; ++i) {
            int k = r - i * D;
            if (k >= 0 && k < 8) {
                SA[k] = fmaf(W[i*3+0], ta0, SA[k]);
                SA[k] = fmaf(W[i*3+1], ta1, SA[k]);
                SA[k] = fmaf(W[i*3+2], ta2, SA[k]);
                SB[k] = fmaf(W[i*3+0], tb0, SB[k]);
                SB[k] = fmaf(W[i*3+1], tb1, SB[k]);
                SB[k] = fmaf(W[i*3+2], tb2, SB[k]);
            }
        }
    }
}

__device__ __forceinline__ void red2(float a, float b2, int lane, float* rs, float* rq) {
#pragma unroll
    for (int off = 32; off; off >>= 1) {
        a  += __shfl_down(a, off, 64);
        b2 += __shfl_down(b2, off, 64);
    }
    if (lane == 0) { *rs = a; *rq = b2; }
}

// grid (9 tiles, 512 b*c), 256 threads. 64x64 tile, both sides, 16 px/thread.
// Plain-store partials; inline wexp (publishes wg); block (0,0) zeroes scal.
__global__ __launch_bounds__(256, 3) void k_stats(
    const float* __restrict__ x,
    const float* __restrict__ we, const float* __restrict__ wd,
    float* __restrict__ part_s, float* __restrict__ part_q,
    float* __restrict__ wg, float* __restrict__ scal) {
    __shared__ float EX[STDH * STSTR], EY[STDH * STSTR];
    __shared__ float wgl[54];
    __shared__ float redS[4][6], redQ[4][6];
    const int tid = threadIdx.x;
    const int p = blockIdx.y;            // b*64 + c
    const int c = p & 63;
    const int b = p >> 6;
    const int t = blockIdx.x;
    const int h0 = (t / 3) * 64, w0 = (t % 3) * 64;

    if (t == 0 && p == 0 && tid < 4) scal[tid] = 0.f;   // for k_fsum (post-boundary)
    if (tid < 54) {                       // this channel's 54 exp'd weights
        int slot = tid / 9, k = tid - slot * 9;
        const float* wsrc = (slot < 3) ? we : wd;
        int br = (slot < 3) ? slot : slot - 3;
        float v = __expf(BETA * wsrc[br * 576 + c * 9 + k]);
        wgl[tid] = v;
        if (t == 0) wg[slot * 576 + c * 9 + k] = v;   // publish for k_reduce (dup-safe)
    }

    const float* xp = x + (size_t)p * HWn;
    {   // pair loader: float2 writes to both planes
        int r = tid / 35, pp = tid - r * 35;
        for (int l = tid; l < SNPAIR; l += 256) {
            int gh = h0 - 3 + r;
            int gw0 = w0 - 3 + 2 * pp;
            float va = 0.f, vb = 0.f;
            if ((unsigned)gh < (unsigned)Hn) {
                if ((unsigned)gw0 < (unsigned)Wn)       va = xp[gh * Wn + gw0];
                if ((unsigned)(gw0+1) < (unsigned)Wn)   vb = xp[gh * Wn + gw0 + 1];
            }
            float ba = BETA * va, bb = BETA * vb;   // OOB -> 0 -> exp(-M), correct
            *(float2*)&EX[r * STSTR + 2 * pp] =
                make_float2(__expf(-ba - MSHIFT), __expf(-bb - MSHIFT));
            *(float2*)&EY[r * STSTR + 2 * pp] =
                make_float2(__expf( ba - MSHIFT), __expf( bb - MSHIFT));
            r += 7; pp += 11;            // 256 = 7*35 + 11
            if (pp >= 35) { pp -= 35; ++r; }
        }
    }
    __syncthreads();

    const int tcol = tid & 31;
    const int py0 = (tid >> 5) * 8;
    const int lane = tid & 63, wv = tid >> 6;
    const float LI = LN2 * INV_BETA, MI = MSHIFT * INV_BETA;

#define DO_BR_STATS(D, SLOT, PL, AL, AM) { \
    float SA[8], SB[8]; \
    sweep2<D>(PL, py0, tcol, &wgl[(SLOT) * 9], SA, SB); \
    float sv = 0.f, qv = 0.f; \
    _Pragma("unroll") \
    for (int k = 0; k < 8; ++k) { \
        float ma = fmaf(__log2f(fmaxf(SA[k], SFLOOR)), AL, AM); \
        float mb = fmaf(__log2f(fmaxf(SB[k], SFLOOR)), AL, AM); \
        sv += ma + mb; qv = fmaf(ma, ma, fmaf(mb, mb, qv)); \
    } \
    red2(sv, qv, lane, &redS[wv][SLOT], &redQ[wv][SLOT]); }

    DO_BR_STATS(1, 0, EX, -LI, -MI)
    DO_BR_STATS(2, 1, EX, -LI, -MI)
    DO_BR_STATS(3, 2, EX, -LI, -MI)
    DO_BR_STATS(1, 3, EY,  LI,  MI)
    DO_BR_STATS(2, 4, EY,  LI,  MI)
    DO_BR_STATS(3, 5, EY,  LI,  MI)
#undef DO_BR_STATS

    __syncthreads();
    if (tid < 6)
        part_s[(tid * 64 + c) * 72 + t * 8 + b] =
            redS[0][tid] + redS[1][tid] + redS[2][tid] + redS[3][tid];
    else if (tid < 12) {
        int v = tid - 6;
        part_q[(v * 64 + c) * 72 + t * 8 + b] =
            redQ[0][v] + redQ[1][v] + redQ[2][v] + redQ[3][v];
    }
}

// grid (48 tiles, 8 b, NS grps), 256 threads. 24x32 tile (3-row strips), NC channels,
// both sides. 1536 blocks @ NS=4 = exactly 6 blocks/CU. alpha from partials in-block;
// slab plain stores ONLY (coherence via kernel boundary).
template<int NS>
__global__ __launch_bounds__(256, 6) void k_reduce(
    const float* __restrict__ x, const float* __restrict__ wg,
    const float* __restrict__ part_s, const float* __restrict__ part_q,
    const float* __restrict__ bn_ge, const float* __restrict__ bn_gd,
    const float* __restrict__ conve, const float* __restrict__ convd,
    float* __restrict__ slab) {
    constexpr int NC = 64 / NS;
    __shared__ float EX[RDH * RSTR], EY[RDH * RSTR];
    __shared__ float al[384];
    const int tid = threadIdx.x;
    const int t = blockIdx.x;            // 48 = 8 row-tiles * 6 col-tiles
    const int b = blockIdx.y;
    const int grp = blockIdx.z;
    const int c0 = grp * NC;
    const int tr = t / 6, tc = t - tr * 6;
    const int h0 = tr * 24, w0 = tc * 32;
    const int px = (tid & 31) + 3;
    const int py0 = (tid >> 5) * 3;      // 3-row strip per thread
    const float* xb = x + (size_t)b * 64 * HWn;

    // alpha for this block's channels only: 6 slots x NC channels
    for (int l = tid; l < 6 * NC; l += 256) {
        int slot = l / NC, cl = l - slot * NC;
        int ai = slot * 64 + c0 + cl;    // al index = side*192 + br*64 + c
        const float* ps = part_s + (size_t)ai * 72;
        const float* pq = part_q + (size_t)ai * 72;
        float s = 0.f, q = 0.f;
#pragma unroll
        for (int j = 0; j < 72; ++j) { s += ps[j]; q += pq[j]; }
        float mean = s * (1.0f / N1);
        float var  = q * (1.0f / N1) - mean * mean;
        float inv  = rsqrtf(fmaxf(var, 0.f) + EPSB);
        int side_ = slot / 3, ch = ai - side_ * 192;
        float g  = side_ ? bn_gd[ch] : bn_ge[ch];
        float cw = side_ ? convd[ch] : conve[ch];
        float sgn = side_ ? 1.f : -1.f;
        al[ai] = sgn * cw * g * inv * INV_BETA * LN2;
    }

    float accE[3] = {0.f, 0.f, 0.f}, accD[3] = {0.f, 0.f, 0.f};
    float2 L[RPITER];

    {   // prologue: prefetch channel c0 (raw x pairs)
        const float* xp = xb + (size_t)c0 * HWn;
        int r = tid / 19, pp = tid - r * 19;
#pragma unroll
        for (int i = 0; i < RPITER; ++i) {
            int l = tid + i * 256;
            float va = 0.f, vb = 0.f;
            if (l < RNPAIR) {
                int gh = h0 - 3 + r, gw0 = w0 - 3 + 2 * pp;
                if ((unsigned)gh < (unsigned)Hn) {
                    if ((unsigned)gw0 < (unsigned)Wn)     va = xp[gh * Wn + gw0];
                    if ((unsigned)(gw0+1) < (unsigned)Wn) vb = xp[gh * Wn + gw0 + 1];
                }
            }
            L[i] = make_float2(va, vb);
            r += 13; pp += 9;            // 256 = 13*19 + 9
            if (pp >= 19) { pp -= 19; ++r; }
        }
    }

    for (int ci = 0; ci < NC; ++ci) {
        __syncthreads();                  // planes free (iter 0: al visible)
        {
            int r = tid / 19, pp = tid - r * 19;
#pragma unroll
            for (int i = 0; i < RPITER; ++i) {
                int l = tid + i * 256;
                if (l < RNPAIR) {
                    float ba = BETA * L[i].x, bb = BETA * L[i].y;
                    *(float2*)&EX[r * RSTR + 2 * pp] =
                        make_float2(__expf(-ba - MSHIFT), __expf(-bb - MSHIFT));
                    *(float2*)&EY[r * RSTR + 2 * pp] =
                        make_float2(__expf( ba - MSHIFT), __expf( bb - MSHIFT));
                }
                r += 13; pp += 9;
                if (pp >= 19) { pp -= 19; ++r; }
            }
        }
        __syncthreads();
        if (ci < NC - 1) {                // prefetch next channel
            const float* xp = xb + (size_t)(c0 + ci + 1) * HWn;
            int r = tid / 19, pp = tid - r * 19;
#pragma unroll
            for (int i = 0; i < RPITER; ++i) {
                int l = tid + i * 256;
                float va = 0.f, vb = 0.f;
                if (l < RNPAIR) {
                    int gh = h0 - 3 + r, gw0 = w0 - 3 + 2 * pp;
                    if ((unsigned)gh < (unsigned)Hn) {
                        if ((unsigned)gw0 < (unsigned)Wn)     va = xp[gh * Wn + gw0];
                        if ((unsigned)(gw0+1) < (unsigned)Wn) vb = xp[gh * Wn + gw0 + 1];
                    }
                }
                L[i] = make_float2(va, vb);
                r += 13; pp += 9;
                if (pp >= 19) { pp -= 19; ++r; }
            }
        }
        const int c = c0 + ci;
#define DO_BR_ACC(D, SIDE, BR, PL, ACC) { \
        float S[3]; \
        sweepT<D, 3, RSTR>(PL, py0, px, wg + ((SIDE) * 3 + (BR)) * 576 + c * 9, S); \
        const float a_ = al[(SIDE) * 192 + (BR) * 64 + c]; \
        _Pragma("unroll") \
        for (int k = 0; k < 3; ++k) \
            ACC[k] = fmaf(a_, __log2f(fmaxf(S[k], SFLOOR)), ACC[k]); }

        DO_BR_ACC(1, 0, 0, EX, accE)
        DO_BR_ACC(2, 0, 1, EX, accE)
        DO_BR_ACC(3, 0, 2, EX, accE)
        DO_BR_ACC(1, 1, 0, EY, accD)
        DO_BR_ACC(2, 1, 1, EY, accD)
        DO_BR_ACC(3, 1, 2, EY, accD)
#undef DO_BR_ACC
    }

    // slab stores (plain, chunk-private; made visible by the kernel boundary)
    float* pe = slab + ((size_t)(grp * 8 + b)) * HWn;
    float* pd = slab + ((size_t)((NS + grp) * 8 + b)) * HWn;
    const int oidx = (h0 + py0) * Wn + (w0 + px - 3);
#pragma unroll
    for (int k = 0; k < 3; ++k) {
        pe[oidx + k * Wn] = accE[k];
        pd[oidx + k * Wn] = accD[k];
    }
}

// sums NS slab groups per pixel -> scalar-BN moments (coherent: post-boundary reads).
template<int NS>
__global__ __launch_bounds__(256) void k_fsum(
    const float* __restrict__ slab, float* __restrict__ scal) {
    int i = blockIdx.x * 256 + threadIdx.x;   // < 294912
    int b = i / HWn, rem = i - b * HWn;
    float e = 0.f, d = 0.f;
#pragma unroll
    for (int g = 0; g < NS; ++g) {
        e += slab[((size_t)(g * 8 + b)) * HWn + rem];
        d += slab[((size_t)((NS + g) * 8 + b)) * HWn + rem];
    }
    float v[4] = {e, e * e, d, d * d};
    __shared__ float red[4][4];
    int lane = threadIdx.x & 63, wv = threadIdx.x >> 6;
#pragma unroll
    for (int k = 0; k < 4; ++k) {
        float tv = v[k];
#pragma unroll
        for (int off = 32; off; off >>= 1) tv += __shfl_down(tv, off, 64);
        if (lane == 0) red[wv][k] = tv;
    }
    __syncthreads();
    if (threadIdx.x < 4)
        atomicAdd(&scal[threadIdx.x],
                  red[0][threadIdx.x] + red[1][threadIdx.x] + red[2][threadIdx.x] + red[3][threadIdx.x]);
}

// re-sums slabs per pixel, applies the scalar BN + ReLU, writes out.
template<int NS>
__global__ __launch_bounds__(256) void k_final(
    const float* __restrict__ slab, const float* __restrict__ scal,
    const float* __restrict__ g_e, const float* __restrict__ b_e,
    const float* __restrict__ g_d, const float* __restrict__ b_d,
    float* __restrict__ out) {
    int i = blockIdx.x * 256 + threadIdx.x;  // < 294912
    int b = i / HWn, rem = i - b * HWn;
    float e = 0.f, d = 0.f;
#pragma unroll
    for (int g = 0; g < NS; ++g) {
        e += slab[((size_t)(g * 8 + b)) * HWn + rem];
        d += slab[((size_t)((NS + g) * 8 + b)) * HWn + rem];
    }
    float me_ = scal[0] * (1.0f / N1);
    float ve  = scal[1] * (1.0f / N1) - me_ * me_;
    float ie  = rsqrtf(fmaxf(ve, 0.f) + EPSB);
    float md_ = scal[2] * (1.0f / N1);
    float vd  = scal[3] * (1.0f / N1) - md_ * md_;
    float idv = rsqrtf(fmaxf(vd, 0.f) + EPSB);
    float oe = fmaxf(g_e[0] * (e - me_) * ie + b_e[0], 0.f);
    float od = fmaxf(g_d[0] * (d - md_) * idv + b_d[0], 0.f);
    out[(size_t)(b * 2) * HWn + rem]     = oe;
    out[(size_t)(b * 2 + 1) * HWn + rem] = od;
}

extern "C" void kernel_launch(void* const* d_in, const int* in_sizes, int n_in,
                              void* d_out, int out_size, void* d_ws, size_t ws_size,
                              hipStream_t stream) {
    const float* x     = (const float*)d_in[0];
    const float* we    = (const float*)d_in[1];
    const float* wd    = (const float*)d_in[2];
    const float* bn_ge = (const float*)d_in[3];
    const float* bn_gd = (const float*)d_in[5];
    const float* conve = (const float*)d_in[7];
    const float* convd = (const float*)d_in[8];
    const float* g_e   = (const float*)d_in[9];
    const float* b_e   = (const float*)d_in[10];
    const float* g_d   = (const float*)d_in[11];
    const float* b_d   = (const float*)d_in[12];
    float* ws = (float*)d_ws;

    float* part_s = ws + WS_PART_S;
    float* part_q = ws + WS_PART_Q;
    float* scal   = ws + WS_SCAL;
    float* wg     = ws + WS_WG;
    float* slab   = ws + WS_SLAB;

    const size_t need4 = (size_t)(WS_SLAB + 8 * 294912) * sizeof(float); // 9.7 MB
    const size_t need2 = (size_t)(WS_SLAB + 4 * 294912) * sizeof(float); // 5.0 MB
    const int ns = (ws_size >= need4) ? 4 : (ws_size >= need2) ? 2 : 1;

    hipLaunchKernelGGL(k_stats, dim3(9, 512), dim3(256), 0, stream,
                       x, we, wd, part_s, part_q, wg, scal);
    if (ns == 4) {
        hipLaunchKernelGGL((k_reduce<4>), dim3(48, 8, 4), dim3(256), 0, stream,
                           x, wg, part_s, part_q, bn_ge, bn_gd, conve, convd, slab);
        hipLaunchKernelGGL((k_fsum<4>), dim3(1152), dim3(256), 0, stream, slab, scal);
        hipLaunchKernelGGL((k_final<4>), dim3(1152), dim3(256), 0, stream,
                           slab, scal, g_e, b_e, g_d, b_d, (float*)d_out);
    } else if (ns == 2) {
        hipLaunchKernelGGL((k_reduce<2>), dim3(48, 8, 2), dim3(256), 0, stream,
                           x, wg, part_s, part_q, bn_ge, bn_gd, conve, convd, slab);
        hipLaunchKernelGGL((k_fsum<2>), dim3(1152), dim3(256), 0, stream, slab, scal);
        hipLaunchKernelGGL((k_final<2>), dim3(1152), dim3(256), 0, stream,
                           slab, scal, g_e, b_e, g_d, b_d, (float*)d_out);
    } else {
        hipLaunchKernelGGL((k_reduce<1>), dim3(48, 8, 1), dim3(256), 0, stream,
                           x, wg, part_s, part_q, bn_ge, bn_gd, conve, convd, slab);
        hipLaunchKernelGGL((k_fsum<1>), dim3(1152), dim3(256), 0, stream, slab, scal);
        hipLaunchKernelGGL((k_final<1>), dim3(1152), dim3(256), 0, stream,
                           slab, scal, g_e, b_e, g_d, b_d, (float*)d_out);
    }
}